// Round 1
// baseline (3848.661 us; speedup 1.0000x reference)
//
#include <hip/hip_runtime.h>
#include <math.h>

// ---------- types / helpers ----------
typedef __attribute__((ext_vector_type(8))) short bf16x8;   // 8 bf16 = 4 VGPR
typedef __attribute__((ext_vector_type(4))) float f32x4;    // MFMA acc
typedef __attribute__((ext_vector_type(4))) unsigned short u16x4;

__device__ __forceinline__ unsigned short f2bf(float x) {   // round-to-nearest-even
  unsigned int u = __builtin_bit_cast(unsigned int, x);
  return (unsigned short)((u + 0x7fffu + ((u >> 16) & 1u)) >> 16);
}
__device__ __forceinline__ float bf2f(unsigned short h) {
  unsigned int u = ((unsigned int)h) << 16;
  return __builtin_bit_cast(float, u);
}

// ---------- K0: convert weights + h0 to bf16 ----------
// regions (fp32 elems): w_i2h 1024x2048 (split->wx,wh), w_h2o 1024x1024, h0 64x1024
__global__ void convert_kernel(const float* __restrict__ w_i2h,
                               const float* __restrict__ w_h2o,
                               const float* __restrict__ h0,
                               unsigned short* __restrict__ wx,
                               unsigned short* __restrict__ wh,
                               unsigned short* __restrict__ w2o,
                               unsigned short* __restrict__ h_all) {
  int idx = blockIdx.x * 256 + threadIdx.x;
  int e = idx * 4;
  const float* src;
  unsigned short* dst;
  if (e < 2097152) {                       // w_i2h
    int row = e >> 11, col = e & 2047;
    src = w_i2h + e;
    dst = (col < 1024) ? (wx + row * 1024 + col) : (wh + row * 1024 + (col - 1024));
  } else if (e < 3145728) {                // w_h2o
    int i = e - 2097152; src = w_h2o + i; dst = w2o + i;
  } else {                                 // h0 -> h_all slice 0
    int i = e - 3145728; src = h0 + i; dst = h_all + i;
  }
  float4 v = *(const float4*)src;
  u16x4 o = {f2bf(v.x), f2bf(v.y), f2bf(v.z), f2bf(v.w)};
  *(u16x4*)dst = o;
}

// ---------- GEMM: C[M,N] = A[M,K] * B[N,K]^T + bias[N] ----------
// 128x128 tile, BK=64, 4 waves (2x2 of 64x64), 16x16x32 bf16 MFMA.
// LDS chunk-XOR swizzle: 16B chunk cc of row stored at cc ^ (row&7).
template <bool AF32, bool OUTBF16>
__global__ __launch_bounds__(256) void gemm_bt(const void* __restrict__ Ap,
                                               const unsigned short* __restrict__ B,
                                               const float* __restrict__ bias,
                                               void* __restrict__ Cp,
                                               int M, int N, int K) {
  __shared__ __attribute__((aligned(16))) unsigned short lA[128 * 64];
  __shared__ __attribute__((aligned(16))) unsigned short lB[128 * 64];
  const int tid = threadIdx.x;
  const int bx = blockIdx.x & 7;       // N/128 == 8
  const int by = blockIdx.x >> 3;
  const int lane = tid & 63, w = tid >> 6;
  const int g = lane >> 4, l15 = lane & 15;
  const int wm = w >> 1, wn = w & 1;

  f32x4 acc[4][4];
#pragma unroll
  for (int i = 0; i < 4; ++i)
#pragma unroll
    for (int j = 0; j < 4; ++j) acc[i][j] = (f32x4){0.f, 0.f, 0.f, 0.f};

  const int nK = K >> 6;
  for (int kt = 0; kt < nK; ++kt) {
    const int k0 = kt << 6;
    // ---- stage A and B tiles (reg-staged, swizzled ds_write) ----
#pragma unroll
    for (int i = 0; i < 4; ++i) {
      int cl = i * 256 + tid;
      int row = cl >> 3, cc = cl & 7;
      bf16x8 av;
      if (AF32) {
        const float* ap = (const float*)Ap + (size_t)(by * 128 + row) * K + k0 + cc * 8;
        float4 f0 = *(const float4*)ap;
        float4 f1 = *(const float4*)(ap + 4);
        av = (bf16x8){(short)f2bf(f0.x), (short)f2bf(f0.y), (short)f2bf(f0.z), (short)f2bf(f0.w),
                      (short)f2bf(f1.x), (short)f2bf(f1.y), (short)f2bf(f1.z), (short)f2bf(f1.w)};
      } else {
        const unsigned short* ap = (const unsigned short*)Ap + (size_t)(by * 128 + row) * K + k0 + cc * 8;
        av = *(const bf16x8*)ap;
      }
      *(bf16x8*)&lA[(row * 8 + (cc ^ (row & 7))) * 8] = av;
      const unsigned short* bp = B + (size_t)(bx * 128 + row) * K + k0 + cc * 8;
      bf16x8 bv = *(const bf16x8*)bp;
      *(bf16x8*)&lB[(row * 8 + (cc ^ (row & 7))) * 8] = bv;
    }
    __syncthreads();
    // ---- compute: 2 k-steps of 32, 16 MFMA each ----
#pragma unroll
    for (int kk = 0; kk < 2; ++kk) {
      bf16x8 av[4], bv[4];
#pragma unroll
      for (int mt = 0; mt < 4; ++mt) {
        int r = wm * 64 + mt * 16 + l15;
        av[mt] = *(const bf16x8*)&lA[(r * 8 + ((kk * 4 + g) ^ (r & 7))) * 8];
      }
#pragma unroll
      for (int nt = 0; nt < 4; ++nt) {
        int r = wn * 64 + nt * 16 + l15;
        bv[nt] = *(const bf16x8*)&lB[(r * 8 + ((kk * 4 + g) ^ (r & 7))) * 8];
      }
#pragma unroll
      for (int mt = 0; mt < 4; ++mt)
#pragma unroll
        for (int nt = 0; nt < 4; ++nt)
          acc[mt][nt] = __builtin_amdgcn_mfma_f32_16x16x32_bf16(av[mt], bv[nt], acc[mt][nt], 0, 0, 0);
    }
    __syncthreads();
  }
  // ---- epilogue: C/D layout row = g*4+r, col = l15 (m89-verified) ----
#pragma unroll
  for (int mt = 0; mt < 4; ++mt) {
    int grow = by * 128 + wm * 64 + mt * 16 + g * 4;
#pragma unroll
    for (int nt = 0; nt < 4; ++nt) {
      int col = bx * 128 + wn * 64 + nt * 16 + l15;
      float bs = bias[col];
#pragma unroll
      for (int r = 0; r < 4; ++r) {
        size_t off = (size_t)(grow + r) * N + col;
        float v = acc[mt][nt][r] + bs;
        if (OUTBF16) ((unsigned short*)Cp)[off] = f2bf(v);
        else ((float*)Cp)[off] = v;
      }
    }
  }
}

// ---------- K2: one recurrence step ----------
// h_next[b,j] = tanh(xp[b,j] + sum_k h_prev[b,k]*wh[j,k]), all 64x1024.
// Grid 64 = 4 bt (16 batches) x 16 jt (64 cols). 4 waves: wave w owns 16 cols.
__global__ __launch_bounds__(256) void rnn_step(const unsigned short* __restrict__ h_prev,
                                                const unsigned short* __restrict__ wh,
                                                const unsigned short* __restrict__ xp,
                                                unsigned short* __restrict__ h_next) {
  __shared__ __attribute__((aligned(16))) unsigned short lH[16 * 1024];  // 32 KB, swizzled
  const int tid = threadIdx.x;
  const int bt = blockIdx.x & 3, jt = blockIdx.x >> 2;
  // stage h rows bt*16..+15 (full K), coalesced global, swizzled ds_write
#pragma unroll
  for (int i = 0; i < 8; ++i) {
    int cl = i * 256 + tid;
    int row = cl >> 7, cc = cl & 127;
    bf16x8 v = *(const bf16x8*)(h_prev + (size_t)(bt * 16 + row) * 1024 + cc * 8);
    *(bf16x8*)&lH[(row * 128 + (cc ^ (row & 7))) * 8] = v;
  }
  __syncthreads();
  const int lane = tid & 63, w = tid >> 6;
  const int g = lane >> 4, l15 = lane & 15;
  const int j = jt * 64 + w * 16 + l15;
  const unsigned short* wrow = wh + (size_t)j * 1024;
  f32x4 acc = (f32x4){0.f, 0.f, 0.f, 0.f};
#pragma unroll 4
  for (int kk = 0; kk < 32; ++kk) {
    bf16x8 av = *(const bf16x8*)&lH[(l15 * 128 + ((kk * 4 + g) ^ (l15 & 7))) * 8];
    bf16x8 bv = *(const bf16x8*)(wrow + kk * 32 + g * 8);
    acc = __builtin_amdgcn_mfma_f32_16x16x32_bf16(av, bv, acc, 0, 0, 0);
  }
#pragma unroll
  for (int r = 0; r < 4; ++r) {
    int b = bt * 16 + g * 4 + r;
    float z = acc[r] + bf2f(xp[(size_t)b * 1024 + j]);
    h_next[(size_t)b * 1024 + j] = f2bf(tanhf(z));
  }
}

// ---------- launch ----------
extern "C" void kernel_launch(void* const* d_in, const int* in_sizes, int n_in,
                              void* d_out, int out_size, void* d_ws, size_t ws_size,
                              hipStream_t stream) {
  const float* x     = (const float*)d_in[0];   // (512,64,1024)
  const float* h0    = (const float*)d_in[1];   // (64,1024)
  const float* w_i2h = (const float*)d_in[2];   // (1024,2048)
  const float* b_i2h = (const float*)d_in[3];   // (1024)
  const float* w_h2o = (const float*)d_in[4];   // (1024,1024)
  const float* b_h2o = (const float*)d_in[5];   // (1024)

  // workspace layout (bytes): h_all (513*64*1024*2 = 67,239,936) | wx 2MB | wh 2MB | w2o 2MB
  char* ws = (char*)d_ws;
  unsigned short* h_all = (unsigned short*)ws;
  unsigned short* wx    = (unsigned short*)(ws + 67239936);
  unsigned short* wh    = wx + 1024 * 1024;
  unsigned short* w2o   = wh + 1024 * 1024;
  // xproj (bf16, 67MB) lives in the first half of d_out; dead before final GEMM writes y.
  unsigned short* xproj = (unsigned short*)d_out;

  convert_kernel<<<3136, 256, 0, stream>>>(w_i2h, w_h2o, h0, wx, wh, w2o, h_all);

  // xproj = x @ wx^T + b_i2h   (M=32768, N=1024, K=1024), fp32 A converted in staging
  gemm_bt<true, true><<<2048, 256, 0, stream>>>((const void*)x, wx, b_i2h,
                                                (void*)xproj, 32768, 1024, 1024);

  // sequential recurrence: h_all[t+1] = tanh(xproj[t] + h_all[t] @ wh^T)
  for (int t = 0; t < 512; ++t) {
    rnn_step<<<64, 256, 0, stream>>>(h_all + (size_t)t * 65536, wh,
                                     xproj + (size_t)t * 65536,
                                     h_all + (size_t)(t + 1) * 65536);
  }

  // Y = h_all[1..512] @ w_h2o^T + b_h2o  -> d_out (fp32)
  gemm_bt<false, false><<<2048, 256, 0, stream>>>((const void*)(h_all + 65536), w2o, b_h2o,
                                                  d_out, 32768, 1024, 1024);
}